// Round 7
// baseline (529.485 us; speedup 1.0000x reference)
//
#include <hip/hip_runtime.h>

// ---------------------------------------------------------------------------
// ResBlock GNN layer on MI355X (gfx950). ALL tensors fp32.
//   h  = gelu(x @ W_ff1 + b)
//   h += seg_sum(gelu(P[src]+Q[dst]+R_e+b_mp)), P=h@Wa, Q=h@Wb, R=ef@Wc  (x2)
//   out = x + h @ W_ff2 + b
// R13: request-count halving. One 128-thread block per 64-edge tile; wave w
// owns channels [w*128,(w+1)*128) at 2 ch/lane (uint loads, 256 B/wave/edge).
// Phase 1: wave computes its channel half for ALL 64 rows (4 sequential
// rt-tiles, one acc[8]); ef rows fetched once per tile. XOR-swizzled 32 KB
// LDS tile (conflict-free store+read, uint read u^(sw<<3)). Phase 2: 8-deep
// double-buffered uint prefetch; interior segments float2 plain-RMW Hacc,
// boundary segments 2x atomicAdd. Edge-walk instruction count and P-request
// count HALVED vs R12 (memory-request-rate was the measured cap: occupancy
// 30->42% bought 0%).
// ---------------------------------------------------------------------------

typedef __attribute__((ext_vector_type(8))) short short8;
typedef __attribute__((ext_vector_type(4))) float f32x4;

#define HD __device__ __forceinline__

HD unsigned short f2bf(float f) {
    unsigned int u = __float_as_uint(f);
    return (unsigned short)((u + 0x7fffu + ((u >> 16) & 1u)) >> 16);  // RNE
}
HD float lo16(unsigned int u) { return __uint_as_float(u << 16); }
HD float hi16(unsigned int u) { return __uint_as_float(u & 0xffff0000u); }
HD float bf2f(unsigned short u) { return __uint_as_float(((unsigned int)u) << 16); }

// gelu tanh-approx via sigmoid identity: 0.5(1+tanh(z)) == sigmoid(2z).
HD float gelu_f(float x) {
    float u = x * (-1.5957691216057308f - 0.07135481627f * (x * x));
    return x * __builtin_amdgcn_rcpf(1.f + __expf(u));
}

// ---------------------------------------------------------------------------
// All 8 weight repacks in one dispatch.
// ---------------------------------------------------------------------------
__global__ void repack_all(const float* __restrict__ Wff1,
                           const float* __restrict__ Wmp1,
                           const float* __restrict__ Wmp2,
                           const float* __restrict__ Wff2,
                           unsigned short* __restrict__ Bp) {
    const int begs[9] = {0, 65536, 131072, 196608, 212992, 278528, 344064,
                         360448, 425984};
    const int srcid[8] = {0, 1, 1, 1, 2, 2, 2, 3};
    const int rowoff[8] = {0, 0, 256, 512, 0, 256, 512, 0};
    int i = blockIdx.x * 256 + threadIdx.x;
    if (i >= 425984) return;
    int s = 0;
#pragma unroll
    for (int k = 1; k < 8; ++k)
        if (i >= begs[k]) s = k;
    const float* Ws[4] = {Wff1, Wmp1, Wmp2, Wff2};
    const float* B = Ws[srcid[s]];
    int local = i - begs[s];
    int k = local >> 8, n = local & 255;
    int kb = k >> 5, kr = k & 31;
    int quad = kr >> 3, j = kr & 7;
    int lane = quad * 16 + (n & 15);
    int nt = n >> 4;
    Bp[begs[s] + ((((kb * 16 + nt) * 64) + lane) << 3) + j] =
        f2bf(B[(size_t)(rowoff[s] + k) * 256 + n]);
}

// ---------------------------------------------------------------------------
// General LDS-free bf16 MFMA GEMM (64x64 tile, grid (ceil(M/64),4)) for FFNs.
// ---------------------------------------------------------------------------
__global__ __launch_bounds__(256) void gemm_kernel(
    const void* __restrict__ Av, int a_is_f32, int M, int K,
    const unsigned short* __restrict__ Bp,
    const float* __restrict__ bias, const float* __restrict__ resid,
    unsigned short* __restrict__ Cb, float* __restrict__ Cf, int do_gelu) {
    int lane = threadIdx.x & 63;
    int w = threadIdx.x >> 6;
    int row0 = blockIdx.x * 64 + w * 16;
    int n0 = blockIdx.y * 64;
    int m15 = lane & 15, quad = lane >> 4;

    int arow = row0 + m15;
    if (arow > M - 1) arow = M - 1;

    f32x4 acc[4] = {{0,0,0,0},{0,0,0,0},{0,0,0,0},{0,0,0,0}};
    const float* Af = (const float*)Av + (size_t)arow * K + quad * 8;
    const unsigned short* Ab = (const unsigned short*)Av + (size_t)arow * K + quad * 8;

    for (int kt = 0; kt < K; kt += 32) {
        short8 a;
        if (a_is_f32) {
            f32x4 lo = *(const f32x4*)(Af + kt);
            f32x4 hi = *(const f32x4*)(Af + kt + 4);
#pragma unroll
            for (int j = 0; j < 4; ++j) {
                a[j] = (short)f2bf(lo[j]);
                a[j + 4] = (short)f2bf(hi[j]);
            }
        } else {
            a = *(const short8*)(Ab + kt);
        }
        const unsigned short* bbase =
            Bp + ((((size_t)(kt >> 5) * 16 + (n0 >> 4)) * 64 + lane) << 3);
#pragma unroll
        for (int nt = 0; nt < 4; ++nt) {
            short8 b = *(const short8*)(bbase + nt * 64 * 8);
            acc[nt] = __builtin_amdgcn_mfma_f32_16x16x32_bf16(a, b, acc[nt], 0, 0, 0);
        }
    }

#pragma unroll
    for (int nt = 0; nt < 4; ++nt) {
        int col = n0 + nt * 16 + m15;
        float bv = bias ? bias[col] : 0.f;
#pragma unroll
        for (int r = 0; r < 4; ++r) {
            int row = row0 + quad * 4 + r;
            if (row < M) {
                float v = acc[nt][r] + bv;
                if (do_gelu) v = gelu_f(v);
                size_t idx = (size_t)row * 256 + col;
                if (resid) v += resid[idx];
                if (Cb) Cb[idx] = f2bf(v);
                if (Cf) Cf[idx] = v;
            }
        }
    }
}

// ---------------------------------------------------------------------------
// P and Q in one dispatch: grid ((M+63)/64, 8); y<4 -> P cols, y>=4 -> Q cols.
// ---------------------------------------------------------------------------
__global__ __launch_bounds__(256) void pq_kernel(
    const unsigned short* __restrict__ A, int M,
    const unsigned short* __restrict__ BpA, const unsigned short* __restrict__ BpB,
    const float* __restrict__ qbias,
    unsigned short* __restrict__ Pb, unsigned short* __restrict__ Qb) {
    int lane = threadIdx.x & 63;
    int w = threadIdx.x >> 6;
    int row0 = blockIdx.x * 64 + w * 16;
    int isQ = blockIdx.y >> 2;
    int n0 = (blockIdx.y & 3) * 64;
    const unsigned short* Bp = isQ ? BpB : BpA;
    unsigned short* out = isQ ? Qb : Pb;
    int m15 = lane & 15, quad = lane >> 4;

    int arow = row0 + m15;
    if (arow > M - 1) arow = M - 1;
    const unsigned short* Ab = A + (size_t)arow * 256 + quad * 8;

    f32x4 acc[4] = {{0,0,0,0},{0,0,0,0},{0,0,0,0},{0,0,0,0}};
    for (int kt = 0; kt < 256; kt += 32) {
        short8 a = *(const short8*)(Ab + kt);
        const unsigned short* bbase =
            Bp + ((((size_t)(kt >> 5) * 16 + (n0 >> 4)) * 64 + lane) << 3);
#pragma unroll
        for (int nt = 0; nt < 4; ++nt) {
            short8 b = *(const short8*)(bbase + nt * 64 * 8);
            acc[nt] = __builtin_amdgcn_mfma_f32_16x16x32_bf16(a, b, acc[nt], 0, 0, 0);
        }
    }

#pragma unroll
    for (int nt = 0; nt < 4; ++nt) {
        int col = n0 + nt * 16 + m15;
        float bv = isQ ? qbias[col] : 0.f;
#pragma unroll
        for (int r = 0; r < 4; ++r) {
            int row = row0 + quad * 4 + r;
            if (row < M) out[(size_t)row * 256 + col] = f2bf(acc[nt][r] + bv);
        }
    }
}

// ---------------------------------------------------------------------------
// Counting sort by dst: zero -> histogram -> single-block scan -> scatter.
// ---------------------------------------------------------------------------
__global__ void zero_i32(int* __restrict__ p, int n) {
    int i = blockIdx.x * 256 + threadIdx.x;
    if (i < n) p[i] = 0;
}
__global__ void hist_kernel(const int* __restrict__ dst, int* __restrict__ cnt, int E) {
    int e = blockIdx.x * 256 + threadIdx.x;
    if (e < E) atomicAdd(&cnt[dst[e]], 1);
}
__global__ __launch_bounds__(1024) void scan_kernel(const int* __restrict__ cnt,
                                                    int* __restrict__ cursor, int N) {
    __shared__ int part[1024];
    int tid = threadIdx.x;
    int per = (N + 1023) / 1024;
    int lo = tid * per;
    int s = 0;
    for (int j = 0; j < per; ++j) {
        int idx = lo + j;
        if (idx < N) s += cnt[idx];
    }
    part[tid] = s;
    __syncthreads();
    for (int off = 1; off < 1024; off <<= 1) {
        int t = (tid >= off) ? part[tid - off] : 0;
        __syncthreads();
        part[tid] += t;
        __syncthreads();
    }
    int run = (tid > 0) ? part[tid - 1] : 0;
    for (int j = 0; j < per; ++j) {
        int idx = lo + j;
        if (idx < N) {
            cursor[idx] = run;
            run += cnt[idx];
        }
    }
}
__global__ void scatter_kernel(const int* __restrict__ src, const int* __restrict__ dst,
                               int* __restrict__ cursor, int* __restrict__ perm,
                               int* __restrict__ srcs, int* __restrict__ dsts, int E) {
    int e = blockIdx.x * 256 + threadIdx.x;
    if (e < E) {
        int d = dst[e];
        int pos = atomicAdd(&cursor[d], 1);
        perm[pos] = e;
        srcs[pos] = src[e];
        dsts[pos] = d;
    }
}

// ---------------------------------------------------------------------------
// FUSED edge kernel. Block = 128 threads (2 waves) = one 64-edge tile, full
// 256 channels. Wave w owns ch [w*128,(w+1)*128), 2 ch/lane (uint).
// Phase 1: R[64 x 256] -> LDS via MFMA; wave w computes its 128-ch half for
//   all 64 rows (4 sequential 16-row tiles, one acc[8]).
//   Swizzle: ushort idx = ch ^ (((row>>2)&3)<<4)  (store via MFMA quad).
// Phase 2: walk 64 edges, 8-deep double-buffered uint prefetch; interior
//   segments float2 plain-RMW Hacc; boundary segments 2x atomicAdd.
// ---------------------------------------------------------------------------
#define LOADB(pv, rv, T0)                                                     \
    _Pragma("unroll") for (int j = 0; j < 8; ++j) {                           \
        int s = __builtin_amdgcn_readlane(vs, (T0) * 8 + j);                  \
        pv[j] = *(const unsigned int*)(Pb + (((size_t)s) << 8) + c0);         \
        rv[j] = tileu[((T0) * 8 + j) * 128 +                                  \
                      (u ^ (((((T0) * 8 + j) >> 2) & 3) << 3))];              \
    }

#define CONS(pv, rv, T0)                                                      \
    _Pragma("unroll") for (int j = 0; j < 8; ++j) {                           \
        int k = (T0) * 8 + j;                                                 \
        if (k > 0) {                                                          \
            int d = __builtin_amdgcn_readlane(vd, k);                         \
            if (d != cur_d) {                                                 \
                float* hp = Hacc + (((size_t)cur_d) << 8) + c0;               \
                if (beg_c >= e_lo && end_c <= e_hi) {                         \
                    hp[0] += ax;                                              \
                    hp[1] += ay;                                              \
                } else {                                                      \
                    atomicAdd(hp, ax);                                        \
                    atomicAdd(hp + 1, ay);                                    \
                }                                                             \
                ax = 0.f; ay = 0.f;                                           \
                cur_d = d;                                                    \
                qu = *(const unsigned int*)(Qb + (((size_t)d) << 8) + c0);    \
                end_c = cursor[d];                                            \
                beg_c = end_c - cnt[d];                                       \
            }                                                                 \
        }                                                                     \
        ax += gelu_f(lo16(pv[j]) + lo16(qu) + lo16(rv[j]));                   \
        ay += gelu_f(hi16(pv[j]) + hi16(qu) + hi16(rv[j]));                   \
    }

__global__ __launch_bounds__(128) void fused_kernel(
    const float* __restrict__ ef, const int* __restrict__ perm,
    const int* __restrict__ srcs, const int* __restrict__ dsts,
    const unsigned short* __restrict__ BpC,
    const unsigned short* __restrict__ Pb, const unsigned short* __restrict__ Qb,
    const int* __restrict__ cursor, const int* __restrict__ cnt,
    float* __restrict__ Hacc, int E) {
    __shared__ unsigned int tileu[64 * 128];  // 32 KB = 64 rows x 256ch bf16
    unsigned short* tiles = (unsigned short*)tileu;
    int lane = threadIdx.x & 63;
    int w = threadIdx.x >> 6;  // 0..1: channel half
    int e_lo = blockIdx.x * 64;
    int n_e = E - e_lo;
    if (n_e > 64) n_e = 64;
    int e_hi = e_lo + n_e;

    // per-lane src/dst of the tile's 64 edges (broadcast via readlane later)
    int eidx = e_lo + lane;
    if (eidx > E - 1) eidx = E - 1;
    int vs = srcs[eidx];
    int vd = dsts[eidx];

    int m15 = lane & 15, quad = lane >> 4;

    // ---- Phase 1: 4 sequential 16-row MFMA tiles, wave's 128-ch half ----
#pragma unroll
    for (int rt = 0; rt < 4; ++rt) {
        int ar = e_lo + rt * 16 + m15;
        if (ar > E - 1) ar = E - 1;
        int g = perm[ar];
        const float* A = ef + (size_t)g * 64 + quad * 8;

        f32x4 acc[8];
#pragma unroll
        for (int nt = 0; nt < 8; ++nt) acc[nt] = {0.f, 0.f, 0.f, 0.f};

#pragma unroll
        for (int kb = 0; kb < 2; ++kb) {
            f32x4 lo = *(const f32x4*)(A + kb * 32);
            f32x4 hi = *(const f32x4*)(A + kb * 32 + 4);
            short8 a;
#pragma unroll
            for (int j = 0; j < 4; ++j) {
                a[j] = (short)f2bf(lo[j]);
                a[j + 4] = (short)f2bf(hi[j]);
            }
#pragma unroll
            for (int nt = 0; nt < 8; ++nt) {
                short8 b = *(const short8*)(
                    BpC + (((size_t)(kb * 16 + w * 8 + nt) * 64 + lane) << 3));
                acc[nt] = __builtin_amdgcn_mfma_f32_16x16x32_bf16(a, b, acc[nt], 0, 0, 0);
            }
        }

        // swizzled store: ushort idx = ch ^ (quad<<4), ch = (w*8+nt)*16+m15
#pragma unroll
        for (int nt = 0; nt < 8; ++nt) {
            int ntg = w * 8 + nt;
            int colp = ((ntg ^ quad) << 4) + m15;
#pragma unroll
            for (int r = 0; r < 4; ++r) {
                int row = rt * 16 + quad * 4 + r;
                tiles[row * 256 + colp] = f2bf(acc[nt][r]);
            }
        }
    }
    __syncthreads();

    // ---- Phase 2: walk 64 edges, 2 ch/lane; u = uint index in row ----
    int u = w * 64 + lane;     // uint index within 128-uint row
    int c0 = u << 1;           // global channel base (2 ch/lane)

    int cur_d = __builtin_amdgcn_readlane(vd, 0);
    unsigned int qu = *(const unsigned int*)(Qb + (((size_t)cur_d) << 8) + c0);
    int end_c = cursor[cur_d];
    int beg_c = end_c - cnt[cur_d];
    float ax = 0.f, ay = 0.f;

    if (n_e == 64) {
        unsigned int pvA[8], rvA[8], pvB[8], rvB[8];
        LOADB(pvA, rvA, 0)
        LOADB(pvB, rvB, 1) CONS(pvA, rvA, 0)
        LOADB(pvA, rvA, 2) CONS(pvB, rvB, 1)
        LOADB(pvB, rvB, 3) CONS(pvA, rvA, 2)
        LOADB(pvA, rvA, 4) CONS(pvB, rvB, 3)
        LOADB(pvB, rvB, 5) CONS(pvA, rvA, 4)
        LOADB(pvA, rvA, 6) CONS(pvB, rvB, 5)
        LOADB(pvB, rvB, 7) CONS(pvA, rvA, 6)
        CONS(pvB, rvB, 7)
    } else {
        // tail tile (E % 64 != 0): simple guarded walk
        for (int k = 0; k < n_e; ++k) {
            int d = __builtin_amdgcn_readlane(vd, k);
            if (k > 0 && d != cur_d) {
                float* hp = Hacc + (((size_t)cur_d) << 8) + c0;
                if (beg_c >= e_lo && end_c <= e_hi) {
                    hp[0] += ax;
                    hp[1] += ay;
                } else {
                    atomicAdd(hp, ax);
                    atomicAdd(hp + 1, ay);
                }
                ax = 0.f; ay = 0.f;
                cur_d = d;
                qu = *(const unsigned int*)(Qb + (((size_t)d) << 8) + c0);
                end_c = cursor[d];
                beg_c = end_c - cnt[d];
            }
            int s = __builtin_amdgcn_readlane(vs, k);
            unsigned int pu = *(const unsigned int*)(Pb + (((size_t)s) << 8) + c0);
            unsigned int ru = tileu[k * 128 + (u ^ (((k >> 2) & 3) << 3))];
            ax += gelu_f(lo16(pu) + lo16(qu) + lo16(ru));
            ay += gelu_f(hi16(pu) + hi16(qu) + hi16(ru));
        }
    }
    {
        float* hp = Hacc + (((size_t)cur_d) << 8) + c0;
        if (beg_c >= e_lo && end_c <= e_hi) {
            hp[0] += ax;
            hp[1] += ay;
        } else {
            atomicAdd(hp, ax);
            atomicAdd(hp + 1, ay);
        }
    }
}

// ---------------------------------------------------------------------------
// h_bf = bf16(Hacc), vectorized (float4 -> uint2). n4 = N*256/4.
// ---------------------------------------------------------------------------
__global__ void finalize_h(const float* __restrict__ Hacc,
                           unsigned short* __restrict__ h_bf, int n4) {
    int i = blockIdx.x * 256 + threadIdx.x;
    if (i < n4) {
        float4 v = ((const float4*)Hacc)[i];
        uint2 o;
        o.x = (unsigned int)f2bf(v.x) | ((unsigned int)f2bf(v.y) << 16);
        o.y = (unsigned int)f2bf(v.z) | ((unsigned int)f2bf(v.w) << 16);
        ((uint2*)h_bf)[i] = o;
    }
}

// ---------------------------------------------------------------------------
extern "C" void kernel_launch(void* const* d_in, const int* in_sizes, int n_in,
                              void* d_out, int out_size, void* d_ws, size_t ws_size,
                              hipStream_t stream) {
    const float* x     = (const float*)d_in[0];
    const int*   ei    = (const int*)d_in[1];
    const float* ef    = (const float*)d_in[2];
    const float* W_ff1 = (const float*)d_in[3];
    const float* b_ff1 = (const float*)d_in[4];
    const float* W_mp1 = (const float*)d_in[5];
    const float* b_mp1 = (const float*)d_in[6];
    const float* W_mp2 = (const float*)d_in[7];
    const float* b_mp2 = (const float*)d_in[8];
    const float* W_ff2 = (const float*)d_in[9];
    const float* b_ff2 = (const float*)d_in[10];

    const int N = in_sizes[0] / 256;  // 10000
    const int E = in_sizes[1] / 2;    // 320000
    const int* src = ei;
    const int* dst = ei + E;

    // ---- workspace carve (256B-aligned bumps) ----
    char* p = (char*)d_ws;
    unsigned short* h_bf = (unsigned short*)p;  p += ((size_t)N * 256 * 2 + 255) & ~255ull;
    unsigned short* Pbuf = (unsigned short*)p;  p += ((size_t)N * 256 * 2 + 255) & ~255ull;
    unsigned short* Qbuf = (unsigned short*)p;  p += ((size_t)N * 256 * 2 + 255) & ~255ull;
    float* Hacc = (float*)p;                    p += ((size_t)N * 256 * 4 + 255) & ~255ull;
    unsigned short* Bp = (unsigned short*)p;    p += (425984ull * 2 + 255) & ~255ull;
    int* cnt    = (int*)p;                      p += ((size_t)N * 4 + 255) & ~255ull;
    int* cursor = (int*)p;                      p += ((size_t)N * 4 + 255) & ~255ull;
    int* perm   = (int*)p;                      p += ((size_t)E * 4 + 255) & ~255ull;
    int* srcs   = (int*)p;                      p += ((size_t)E * 4 + 255) & ~255ull;
    int* dsts   = (int*)p;                      p += ((size_t)E * 4 + 255) & ~255ull;

    unsigned short* Bp_ff1 = Bp + 0;
    unsigned short* Bp_a1  = Bp + 65536;
    unsigned short* Bp_b1  = Bp + 131072;
    unsigned short* Bp_c1  = Bp + 196608;
    unsigned short* Bp_a2  = Bp + 212992;
    unsigned short* Bp_b2  = Bp + 278528;
    unsigned short* Bp_c2  = Bp + 344064;
    unsigned short* Bp_ff2 = Bp + 360448;

    // ---- repack all weights (single dispatch) ----
    repack_all<<<1664, 256, 0, stream>>>(W_ff1, W_mp1, W_mp2, W_ff2, Bp);

    // ---- counting sort of edges by dst (CSR) ----
    zero_i32<<<(N + 255) / 256, 256, 0, stream>>>(cnt, N);
    hist_kernel<<<(E + 255) / 256, 256, 0, stream>>>(dst, cnt, E);
    scan_kernel<<<1, 1024, 0, stream>>>(cnt, cursor, N);
    scatter_kernel<<<(E + 255) / 256, 256, 0, stream>>>(src, dst, cursor, perm, srcs,
                                                        dsts, E);

    dim3 gN((N + 63) / 64, 4);
    dim3 gPQ((N + 63) / 64, 8);
    int n_tiles = (E + 63) / 64;

    // ---- FFN1: h = gelu(x@W_ff1 + b); h_bf for GEMMs, Hacc = f32 accumulator
    gemm_kernel<<<gN, 256, 0, stream>>>(x, 1, N, 256, Bp_ff1, b_ff1, nullptr,
                                        h_bf, Hacc, 1);

    const unsigned short* Bp_a[2] = {Bp_a1, Bp_a2};
    const unsigned short* Bp_b[2] = {Bp_b1, Bp_b2};
    const unsigned short* Bp_c[2] = {Bp_c1, Bp_c2};
    const float* bmp[2] = {b_mp1, b_mp2};

    for (int l = 0; l < 2; ++l) {
        pq_kernel<<<gPQ, 256, 0, stream>>>(h_bf, N, Bp_a[l], Bp_b[l], bmp[l],
                                           Pbuf, Qbuf);
        fused_kernel<<<n_tiles, 128, 0, stream>>>(
            ef, perm, srcs, dsts, Bp_c[l], Pbuf, Qbuf, cursor, cnt, Hacc, E);
        if (l == 0)
            finalize_h<<<(N * 64 + 255) / 256, 256, 0, stream>>>(Hacc, h_bf, N * 64);
    }

    // ---- FFN2: out = x + bf16(Hacc)@W_ff2 + b  (reads Hacc directly) ----
    gemm_kernel<<<gN, 256, 0, stream>>>(Hacc, 1, N, 256, Bp_ff2, b_ff2, x,
                                        nullptr, (float*)d_out, 0);
}

// Round 8
// 471.592 us; speedup vs baseline: 1.1228x; 1.1228x over previous
//
#include <hip/hip_runtime.h>

// ---------------------------------------------------------------------------
// ResBlock GNN layer on MI355X (gfx950). ALL tensors fp32.
//   h  = gelu(x @ W_ff1 + b)
//   h += seg_sum(gelu(P[src]+Q[dst]+R_e+b_mp)), P=h@Wa, Q=h@Wb, R=ef@Wc  (x2)
//   out = x + h @ W_ff2 + b
// R14: R11 structure (best measured) + TRIPLE-buffered phase-2 prefetch.
//  - Block = 128 thr (2 waves) = 64-edge tile x 128-ch half; 16 KB LDS;
//    1 ch/lane; parallel acc[2][8] phase 1 (R11's proven 123us config).
//  - Phase 2 pipeline deepened: LOADB(t+2) issued before CONS(t) -> 16-24
//    loads in flight/wave (~1100 cyc slack > 900 cyc HBM gather latency).
//    R12/R13 showed more WAVES don't help past R11's level; per-wave DEPTH
//    is the untested lever for the latency-bound P-gather.
//  - Segment-state loads (Q row, cursor, cnt) hoisted above phase 1 so their
//    latency hides under MFMA.
//  - XOR-swizzled LDS (0 conflicts), interior plain-RMW / boundary atomicAdd.
// ---------------------------------------------------------------------------

typedef __attribute__((ext_vector_type(8))) short short8;
typedef __attribute__((ext_vector_type(4))) float f32x4;

#define HD __device__ __forceinline__

HD unsigned short f2bf(float f) {
    unsigned int u = __float_as_uint(f);
    return (unsigned short)((u + 0x7fffu + ((u >> 16) & 1u)) >> 16);  // RNE
}
HD float lo16(unsigned int u) { return __uint_as_float(u << 16); }
HD float hi16(unsigned int u) { return __uint_as_float(u & 0xffff0000u); }
HD float bf2f(unsigned short u) { return __uint_as_float(((unsigned int)u) << 16); }

// gelu tanh-approx via sigmoid identity: 0.5(1+tanh(z)) == sigmoid(2z).
HD float gelu_f(float x) {
    float u = x * (-1.5957691216057308f - 0.07135481627f * (x * x));
    return x * __builtin_amdgcn_rcpf(1.f + __expf(u));
}

// ---------------------------------------------------------------------------
// All 8 weight repacks in one dispatch.
// ---------------------------------------------------------------------------
__global__ void repack_all(const float* __restrict__ Wff1,
                           const float* __restrict__ Wmp1,
                           const float* __restrict__ Wmp2,
                           const float* __restrict__ Wff2,
                           unsigned short* __restrict__ Bp) {
    const int begs[9] = {0, 65536, 131072, 196608, 212992, 278528, 344064,
                         360448, 425984};
    const int srcid[8] = {0, 1, 1, 1, 2, 2, 2, 3};
    const int rowoff[8] = {0, 0, 256, 512, 0, 256, 512, 0};
    int i = blockIdx.x * 256 + threadIdx.x;
    if (i >= 425984) return;
    int s = 0;
#pragma unroll
    for (int k = 1; k < 8; ++k)
        if (i >= begs[k]) s = k;
    const float* Ws[4] = {Wff1, Wmp1, Wmp2, Wff2};
    const float* B = Ws[srcid[s]];
    int local = i - begs[s];
    int k = local >> 8, n = local & 255;
    int kb = k >> 5, kr = k & 31;
    int quad = kr >> 3, j = kr & 7;
    int lane = quad * 16 + (n & 15);
    int nt = n >> 4;
    Bp[begs[s] + ((((kb * 16 + nt) * 64) + lane) << 3) + j] =
        f2bf(B[(size_t)(rowoff[s] + k) * 256 + n]);
}

// ---------------------------------------------------------------------------
// General LDS-free bf16 MFMA GEMM (64x64 tile, grid (ceil(M/64),4)) for FFNs.
// ---------------------------------------------------------------------------
__global__ __launch_bounds__(256) void gemm_kernel(
    const void* __restrict__ Av, int a_is_f32, int M, int K,
    const unsigned short* __restrict__ Bp,
    const float* __restrict__ bias, const float* __restrict__ resid,
    unsigned short* __restrict__ Cb, float* __restrict__ Cf, int do_gelu) {
    int lane = threadIdx.x & 63;
    int w = threadIdx.x >> 6;
    int row0 = blockIdx.x * 64 + w * 16;
    int n0 = blockIdx.y * 64;
    int m15 = lane & 15, quad = lane >> 4;

    int arow = row0 + m15;
    if (arow > M - 1) arow = M - 1;

    f32x4 acc[4] = {{0,0,0,0},{0,0,0,0},{0,0,0,0},{0,0,0,0}};
    const float* Af = (const float*)Av + (size_t)arow * K + quad * 8;
    const unsigned short* Ab = (const unsigned short*)Av + (size_t)arow * K + quad * 8;

    for (int kt = 0; kt < K; kt += 32) {
        short8 a;
        if (a_is_f32) {
            f32x4 lo = *(const f32x4*)(Af + kt);
            f32x4 hi = *(const f32x4*)(Af + kt + 4);
#pragma unroll
            for (int j = 0; j < 4; ++j) {
                a[j] = (short)f2bf(lo[j]);
                a[j + 4] = (short)f2bf(hi[j]);
            }
        } else {
            a = *(const short8*)(Ab + kt);
        }
        const unsigned short* bbase =
            Bp + ((((size_t)(kt >> 5) * 16 + (n0 >> 4)) * 64 + lane) << 3);
#pragma unroll
        for (int nt = 0; nt < 4; ++nt) {
            short8 b = *(const short8*)(bbase + nt * 64 * 8);
            acc[nt] = __builtin_amdgcn_mfma_f32_16x16x32_bf16(a, b, acc[nt], 0, 0, 0);
        }
    }

#pragma unroll
    for (int nt = 0; nt < 4; ++nt) {
        int col = n0 + nt * 16 + m15;
        float bv = bias ? bias[col] : 0.f;
#pragma unroll
        for (int r = 0; r < 4; ++r) {
            int row = row0 + quad * 4 + r;
            if (row < M) {
                float v = acc[nt][r] + bv;
                if (do_gelu) v = gelu_f(v);
                size_t idx = (size_t)row * 256 + col;
                if (resid) v += resid[idx];
                if (Cb) Cb[idx] = f2bf(v);
                if (Cf) Cf[idx] = v;
            }
        }
    }
}

// ---------------------------------------------------------------------------
// P and Q in one dispatch: grid ((M+63)/64, 8); y<4 -> P cols, y>=4 -> Q cols.
// ---------------------------------------------------------------------------
__global__ __launch_bounds__(256) void pq_kernel(
    const unsigned short* __restrict__ A, int M,
    const unsigned short* __restrict__ BpA, const unsigned short* __restrict__ BpB,
    const float* __restrict__ qbias,
    unsigned short* __restrict__ Pb, unsigned short* __restrict__ Qb) {
    int lane = threadIdx.x & 63;
    int w = threadIdx.x >> 6;
    int row0 = blockIdx.x * 64 + w * 16;
    int isQ = blockIdx.y >> 2;
    int n0 = (blockIdx.y & 3) * 64;
    const unsigned short* Bp = isQ ? BpB : BpA;
    unsigned short* out = isQ ? Qb : Pb;
    int m15 = lane & 15, quad = lane >> 4;

    int arow = row0 + m15;
    if (arow > M - 1) arow = M - 1;
    const unsigned short* Ab = A + (size_t)arow * 256 + quad * 8;

    f32x4 acc[4] = {{0,0,0,0},{0,0,0,0},{0,0,0,0},{0,0,0,0}};
    for (int kt = 0; kt < 256; kt += 32) {
        short8 a = *(const short8*)(Ab + kt);
        const unsigned short* bbase =
            Bp + ((((size_t)(kt >> 5) * 16 + (n0 >> 4)) * 64 + lane) << 3);
#pragma unroll
        for (int nt = 0; nt < 4; ++nt) {
            short8 b = *(const short8*)(bbase + nt * 64 * 8);
            acc[nt] = __builtin_amdgcn_mfma_f32_16x16x32_bf16(a, b, acc[nt], 0, 0, 0);
        }
    }

#pragma unroll
    for (int nt = 0; nt < 4; ++nt) {
        int col = n0 + nt * 16 + m15;
        float bv = isQ ? qbias[col] : 0.f;
#pragma unroll
        for (int r = 0; r < 4; ++r) {
            int row = row0 + quad * 4 + r;
            if (row < M) out[(size_t)row * 256 + col] = f2bf(acc[nt][r] + bv);
        }
    }
}

// ---------------------------------------------------------------------------
// Counting sort by dst: zero -> histogram -> single-block scan -> scatter.
// ---------------------------------------------------------------------------
__global__ void zero_i32(int* __restrict__ p, int n) {
    int i = blockIdx.x * 256 + threadIdx.x;
    if (i < n) p[i] = 0;
}
__global__ void hist_kernel(const int* __restrict__ dst, int* __restrict__ cnt, int E) {
    int e = blockIdx.x * 256 + threadIdx.x;
    if (e < E) atomicAdd(&cnt[dst[e]], 1);
}
__global__ __launch_bounds__(1024) void scan_kernel(const int* __restrict__ cnt,
                                                    int* __restrict__ cursor, int N) {
    __shared__ int part[1024];
    int tid = threadIdx.x;
    int per = (N + 1023) / 1024;
    int lo = tid * per;
    int s = 0;
    for (int j = 0; j < per; ++j) {
        int idx = lo + j;
        if (idx < N) s += cnt[idx];
    }
    part[tid] = s;
    __syncthreads();
    for (int off = 1; off < 1024; off <<= 1) {
        int t = (tid >= off) ? part[tid - off] : 0;
        __syncthreads();
        part[tid] += t;
        __syncthreads();
    }
    int run = (tid > 0) ? part[tid - 1] : 0;
    for (int j = 0; j < per; ++j) {
        int idx = lo + j;
        if (idx < N) {
            cursor[idx] = run;
            run += cnt[idx];
        }
    }
}
__global__ void scatter_kernel(const int* __restrict__ src, const int* __restrict__ dst,
                               int* __restrict__ cursor, int* __restrict__ perm,
                               int* __restrict__ srcs, int* __restrict__ dsts, int E) {
    int e = blockIdx.x * 256 + threadIdx.x;
    if (e < E) {
        int d = dst[e];
        int pos = atomicAdd(&cursor[d], 1);
        perm[pos] = e;
        srcs[pos] = src[e];
        dsts[pos] = d;
    }
}

// ---------------------------------------------------------------------------
// FUSED edge kernel. Block = 128 threads (2 waves) = 64-edge tile x 128-ch
// half. grid = 2*ceil(E/64); tile_id = bid>>1, half = bid&1.
// Phase 1: R[64 x 128ch] = bf16(ef[perm[e]] @ Wc[:, half]) -> LDS (MFMA),
//   XOR-swizzled: store col' = col ^ (quad<<4) -> conflict-free store+read.
// Phase 2: c = half*128 + tid; both waves walk all 64 edges with TRIPLE-
//   buffered prefetch (LOADB(t+2) before CONS(t) -> 16-24 loads in flight).
//   Interior segments plain-RMW Hacc; boundary segments atomicAdd.
// ---------------------------------------------------------------------------
#define LOADB(pv, rv, T0)                                                     \
    _Pragma("unroll") for (int j = 0; j < 8; ++j) {                           \
        int s = __builtin_amdgcn_readlane(vs, (T0) * 8 + j);                  \
        pv[j] = bf2f(Pb[((size_t)s << 8) + c]);                               \
        rv[j] = bf2f(tile[((T0) * 8 + j) * 128 +                              \
                          (c_local ^ (((((T0) * 8 + j) >> 2) & 3) << 4))]);   \
    }

#define CONS(pv, rv, T0)                                                      \
    _Pragma("unroll") for (int j = 0; j < 8; ++j) {                           \
        int k = (T0) * 8 + j;                                                 \
        if (k > 0) {                                                          \
            int d = __builtin_amdgcn_readlane(vd, k);                         \
            if (d != cur_d) {                                                 \
                size_t hidx = ((size_t)cur_d << 8) + c;                       \
                if (beg_c >= e_lo && end_c <= e_hi)                           \
                    Hacc[hidx] += a;                                          \
                else                                                          \
                    atomicAdd(&Hacc[hidx], a);                                \
                a = 0.f;                                                      \
                cur_d = d;                                                    \
                qv = bf2f(Qb[((size_t)d << 8) + c]);                          \
                end_c = cursor[d];                                            \
                beg_c = end_c - cnt[d];                                       \
            }                                                                 \
        }                                                                     \
        a += gelu_f(pv[j] + qv + rv[j]);                                      \
    }

__global__ __launch_bounds__(128) void fused_kernel(
    const float* __restrict__ ef, const int* __restrict__ perm,
    const int* __restrict__ srcs, const int* __restrict__ dsts,
    const unsigned short* __restrict__ BpC,
    const unsigned short* __restrict__ Pb, const unsigned short* __restrict__ Qb,
    const int* __restrict__ cursor, const int* __restrict__ cnt,
    float* __restrict__ Hacc, int E) {
    __shared__ unsigned short tile[64 * 128];  // 16 KB, swizzled R half-tile
    int lane = threadIdx.x & 63;
    int w = threadIdx.x >> 6;  // 0..1
    int tile_id = blockIdx.x >> 1;
    int half = blockIdx.x & 1;
    int e_lo = tile_id * 64;
    int n_e = E - e_lo;
    if (n_e > 64) n_e = 64;
    int e_hi = e_lo + n_e;

    // per-lane src/dst of the tile's 64 edges (broadcast via readlane later)
    int eidx = e_lo + lane;
    if (eidx > E - 1) eidx = E - 1;
    int vs = srcs[eidx];
    int vd = dsts[eidx];

    int m15 = lane & 15, quad = lane >> 4;

    // hoisted phase-2 segment state: latency hides under phase-1 MFMA
    int c_local = threadIdx.x;          // 0..127
    int c = (half << 7) + c_local;      // global channel
    int cur_d = __builtin_amdgcn_readlane(vd, 0);
    float qv = bf2f(Qb[((size_t)cur_d << 8) + c]);
    int end_c = cursor[cur_d];
    int beg_c = end_c - cnt[cur_d];

    // ---- Phase 1: MFMA R half-tile. Wave w: rows w*32 + rt*16. ----
    int ar0 = e_lo + w * 32 + m15;
    int ar1 = ar0 + 16;
    if (ar0 > E - 1) ar0 = E - 1;
    if (ar1 > E - 1) ar1 = E - 1;
    int g0 = perm[ar0], g1 = perm[ar1];
    const float* A0 = ef + (size_t)g0 * 64 + quad * 8;
    const float* A1 = ef + (size_t)g1 * 64 + quad * 8;

    f32x4 acc[2][8];
#pragma unroll
    for (int rt = 0; rt < 2; ++rt)
#pragma unroll
        for (int nt = 0; nt < 8; ++nt) acc[rt][nt] = {0.f, 0.f, 0.f, 0.f};

#pragma unroll
    for (int kb = 0; kb < 2; ++kb) {
        f32x4 lo0 = *(const f32x4*)(A0 + kb * 32);
        f32x4 hi0 = *(const f32x4*)(A0 + kb * 32 + 4);
        f32x4 lo1 = *(const f32x4*)(A1 + kb * 32);
        f32x4 hi1 = *(const f32x4*)(A1 + kb * 32 + 4);
        short8 a0, a1;
#pragma unroll
        for (int j = 0; j < 4; ++j) {
            a0[j] = (short)f2bf(lo0[j]);
            a0[j + 4] = (short)f2bf(hi0[j]);
            a1[j] = (short)f2bf(lo1[j]);
            a1[j + 4] = (short)f2bf(hi1[j]);
        }
#pragma unroll
        for (int nt = 0; nt < 8; ++nt) {
            short8 b = *(const short8*)(
                BpC + (((size_t)(kb * 16 + half * 8 + nt) * 64 + lane) << 3));
            acc[0][nt] = __builtin_amdgcn_mfma_f32_16x16x32_bf16(a0, b, acc[0][nt], 0, 0, 0);
            acc[1][nt] = __builtin_amdgcn_mfma_f32_16x16x32_bf16(a1, b, acc[1][nt], 0, 0, 0);
        }
    }

    // swizzled store: col' = (nt^quad)*16 + m15  (channel nt*16+m15)
#pragma unroll
    for (int rt = 0; rt < 2; ++rt)
#pragma unroll
        for (int nt = 0; nt < 8; ++nt) {
            int colp = ((nt ^ quad) << 4) + m15;
#pragma unroll
            for (int r = 0; r < 4; ++r) {
                int row = w * 32 + rt * 16 + quad * 4 + r;
                tile[row * 128 + colp] = f2bf(acc[rt][nt][r]);
            }
        }
    __syncthreads();

    // ---- Phase 2: both waves walk all 64 edges; triple-buffered ----
    float a = 0.f;

    if (n_e == 64) {
        float pvA[8], rvA[8], pvB[8], rvB[8], pvC[8], rvC[8];
        LOADB(pvA, rvA, 0)
        LOADB(pvB, rvB, 1)
        LOADB(pvC, rvC, 2) CONS(pvA, rvA, 0)
        LOADB(pvA, rvA, 3) CONS(pvB, rvB, 1)
        LOADB(pvB, rvB, 4) CONS(pvC, rvC, 2)
        LOADB(pvC, rvC, 5) CONS(pvA, rvA, 3)
        LOADB(pvA, rvA, 6) CONS(pvB, rvB, 4)
        LOADB(pvB, rvB, 7) CONS(pvC, rvC, 5)
        CONS(pvA, rvA, 6)
        CONS(pvB, rvB, 7)
    } else {
        // tail tile (E % 64 != 0): simple guarded walk
        for (int k = 0; k < n_e; ++k) {
            int d = __builtin_amdgcn_readlane(vd, k);
            if (k > 0 && d != cur_d) {
                size_t hidx = ((size_t)cur_d << 8) + c;
                if (beg_c >= e_lo && end_c <= e_hi)
                    Hacc[hidx] += a;
                else
                    atomicAdd(&Hacc[hidx], a);
                a = 0.f;
                cur_d = d;
                qv = bf2f(Qb[((size_t)d << 8) + c]);
                end_c = cursor[d];
                beg_c = end_c - cnt[d];
            }
            int s = __builtin_amdgcn_readlane(vs, k);
            float pv = bf2f(Pb[((size_t)s << 8) + c]);
            float rv = bf2f(tile[k * 128 + (c_local ^ (((k >> 2) & 3) << 4))]);
            a += gelu_f(pv + qv + rv);
        }
    }
    {
        size_t hidx = ((size_t)cur_d << 8) + c;
        if (beg_c >= e_lo && end_c <= e_hi)
            Hacc[hidx] += a;
        else
            atomicAdd(&Hacc[hidx], a);
    }
}

// ---------------------------------------------------------------------------
// h_bf = bf16(Hacc), vectorized (float4 -> uint2). n4 = N*256/4.
// ---------------------------------------------------------------------------
__global__ void finalize_h(const float* __restrict__ Hacc,
                           unsigned short* __restrict__ h_bf, int n4) {
    int i = blockIdx.x * 256 + threadIdx.x;
    if (i < n4) {
        float4 v = ((const float4*)Hacc)[i];
        uint2 o;
        o.x = (unsigned int)f2bf(v.x) | ((unsigned int)f2bf(v.y) << 16);
        o.y = (unsigned int)f2bf(v.z) | ((unsigned int)f2bf(v.w) << 16);
        ((uint2*)h_bf)[i] = o;
    }
}

// ---------------------------------------------------------------------------
extern "C" void kernel_launch(void* const* d_in, const int* in_sizes, int n_in,
                              void* d_out, int out_size, void* d_ws, size_t ws_size,
                              hipStream_t stream) {
    const float* x     = (const float*)d_in[0];
    const int*   ei    = (const int*)d_in[1];
    const float* ef    = (const float*)d_in[2];
    const float* W_ff1 = (const float*)d_in[3];
    const float* b_ff1 = (const float*)d_in[4];
    const float* W_mp1 = (const float*)d_in[5];
    const float* b_mp1 = (const float*)d_in[6];
    const float* W_mp2 = (const float*)d_in[7];
    const float* b_mp2 = (const float*)d_in[8];
    const float* W_ff2 = (const float*)d_in[9];
    const float* b_ff2 = (const float*)d_in[10];

    const int N = in_sizes[0] / 256;  // 10000
    const int E = in_sizes[1] / 2;    // 320000
    const int* src = ei;
    const int* dst = ei + E;

    // ---- workspace carve (256B-aligned bumps) ----
    char* p = (char*)d_ws;
    unsigned short* h_bf = (unsigned short*)p;  p += ((size_t)N * 256 * 2 + 255) & ~255ull;
    unsigned short* Pbuf = (unsigned short*)p;  p += ((size_t)N * 256 * 2 + 255) & ~255ull;
    unsigned short* Qbuf = (unsigned short*)p;  p += ((size_t)N * 256 * 2 + 255) & ~255ull;
    float* Hacc = (float*)p;                    p += ((size_t)N * 256 * 4 + 255) & ~255ull;
    unsigned short* Bp = (unsigned short*)p;    p += (425984ull * 2 + 255) & ~255ull;
    int* cnt    = (int*)p;                      p += ((size_t)N * 4 + 255) & ~255ull;
    int* cursor = (int*)p;                      p += ((size_t)N * 4 + 255) & ~255ull;
    int* perm   = (int*)p;                      p += ((size_t)E * 4 + 255) & ~255ull;
    int* srcs   = (int*)p;                      p += ((size_t)E * 4 + 255) & ~255ull;
    int* dsts   = (int*)p;                      p += ((size_t)E * 4 + 255) & ~255ull;

    unsigned short* Bp_ff1 = Bp + 0;
    unsigned short* Bp_a1  = Bp + 65536;
    unsigned short* Bp_b1  = Bp + 131072;
    unsigned short* Bp_c1  = Bp + 196608;
    unsigned short* Bp_a2  = Bp + 212992;
    unsigned short* Bp_b2  = Bp + 278528;
    unsigned short* Bp_c2  = Bp + 344064;
    unsigned short* Bp_ff2 = Bp + 360448;

    // ---- repack all weights (single dispatch) ----
    repack_all<<<1664, 256, 0, stream>>>(W_ff1, W_mp1, W_mp2, W_ff2, Bp);

    // ---- counting sort of edges by dst (CSR) ----
    zero_i32<<<(N + 255) / 256, 256, 0, stream>>>(cnt, N);
    hist_kernel<<<(E + 255) / 256, 256, 0, stream>>>(dst, cnt, E);
    scan_kernel<<<1, 1024, 0, stream>>>(cnt, cursor, N);
    scatter_kernel<<<(E + 255) / 256, 256, 0, stream>>>(src, dst, cursor, perm, srcs,
                                                        dsts, E);

    dim3 gN((N + 63) / 64, 4);
    dim3 gPQ((N + 63) / 64, 8);
    int n_tiles = (E + 63) / 64;

    // ---- FFN1: h = gelu(x@W_ff1 + b); h_bf for GEMMs, Hacc = f32 accumulator
    gemm_kernel<<<gN, 256, 0, stream>>>(x, 1, N, 256, Bp_ff1, b_ff1, nullptr,
                                        h_bf, Hacc, 1);

    const unsigned short* Bp_a[2] = {Bp_a1, Bp_a2};
    const unsigned short* Bp_b[2] = {Bp_b1, Bp_b2};
    const unsigned short* Bp_c[2] = {Bp_c1, Bp_c2};
    const float* bmp[2] = {b_mp1, b_mp2};

    for (int l = 0; l < 2; ++l) {
        pq_kernel<<<gPQ, 256, 0, stream>>>(h_bf, N, Bp_a[l], Bp_b[l], bmp[l],
                                           Pbuf, Qbuf);
        fused_kernel<<<n_tiles * 2, 128, 0, stream>>>(
            ef, perm, srcs, dsts, Bp_c[l], Pbuf, Qbuf, cursor, cnt, Hacc, E);
        if (l == 0)
            finalize_h<<<(N * 64 + 255) / 256, 256, 0, stream>>>(Hacc, h_bf, N * 64);
    }

    // ---- FFN2: out = x + bf16(Hacc)@W_ff2 + b  (reads Hacc directly) ----
    gemm_kernel<<<gN, 256, 0, stream>>>(Hacc, 1, N, 256, Bp_ff2, b_ff2, x,
                                        nullptr, (float*)d_out, 0);
}

// Round 9
// 412.691 us; speedup vs baseline: 1.2830x; 1.1427x over previous
//
#include <hip/hip_runtime.h>

// ---------------------------------------------------------------------------
// ResBlock GNN layer on MI355X (gfx950). ALL tensors fp32.
//   h  = gelu(x @ W_ff1 + b)
//   h += seg_sum(gelu(P[src]+Q[dst]+R_e+b_mp)), P=h@Wa, Q=h@Wb, R=ef@Wc  (x2)
//   out = x + h @ W_ff2 + b
// R15: 4ch/lane fused kernel with cross-wave carry merge.
//  - Block = 256 thr (4 waves) = one 64-edge tile, full 256 channels.
//  - Phase 1: original rgemm body (wave w -> rows w*16..+15, acc[16]) with
//    XOR-swizzled LDS store (col group ^= quad).
//  - Phase 2: wave w walks ONLY its own 16 rows (self-produced -> no barrier
//    between phases). 4 ch/lane uint2: ONE wave covers all 256 channels ->
//    per-edge overhead and P-request count / 4 vs R14 (measured cap was
//    issued work: VALU-busy cycles matched instr-count model; concurrency
//    levers R12-R14 all flat).
//  - Segments interior to a wave window: plain RMW (unique writer).
//    Wave-boundary partials -> carry rows in LDS (aliased onto dead R tile
//    after barrier) -> 256-thread segmented merge -> interior runs plain
//    RMW, block-boundary runs atomicAdd (<=2/block, WRITE stays ~15MB).
// ---------------------------------------------------------------------------

typedef __attribute__((ext_vector_type(8))) short short8;
typedef __attribute__((ext_vector_type(4))) float f32x4;

#define HD __device__ __forceinline__

HD unsigned short f2bf(float f) {
    unsigned int u = __float_as_uint(f);
    return (unsigned short)((u + 0x7fffu + ((u >> 16) & 1u)) >> 16);  // RNE
}
HD float lo16(unsigned int u) { return __uint_as_float(u << 16); }
HD float hi16(unsigned int u) { return __uint_as_float(u & 0xffff0000u); }
HD float bf2f(unsigned short u) { return __uint_as_float(((unsigned int)u) << 16); }

// gelu tanh-approx via sigmoid identity: 0.5(1+tanh(z)) == sigmoid(2z).
HD float gelu_f(float x) {
    float u = x * (-1.5957691216057308f - 0.07135481627f * (x * x));
    return x * __builtin_amdgcn_rcpf(1.f + __expf(u));
}

// ---------------------------------------------------------------------------
// All 8 weight repacks in one dispatch.
// ---------------------------------------------------------------------------
__global__ void repack_all(const float* __restrict__ Wff1,
                           const float* __restrict__ Wmp1,
                           const float* __restrict__ Wmp2,
                           const float* __restrict__ Wff2,
                           unsigned short* __restrict__ Bp) {
    const int begs[9] = {0, 65536, 131072, 196608, 212992, 278528, 344064,
                         360448, 425984};
    const int srcid[8] = {0, 1, 1, 1, 2, 2, 2, 3};
    const int rowoff[8] = {0, 0, 256, 512, 0, 256, 512, 0};
    int i = blockIdx.x * 256 + threadIdx.x;
    if (i >= 425984) return;
    int s = 0;
#pragma unroll
    for (int k = 1; k < 8; ++k)
        if (i >= begs[k]) s = k;
    const float* Ws[4] = {Wff1, Wmp1, Wmp2, Wff2};
    const float* B = Ws[srcid[s]];
    int local = i - begs[s];
    int k = local >> 8, n = local & 255;
    int kb = k >> 5, kr = k & 31;
    int quad = kr >> 3, j = kr & 7;
    int lane = quad * 16 + (n & 15);
    int nt = n >> 4;
    Bp[begs[s] + ((((kb * 16 + nt) * 64) + lane) << 3) + j] =
        f2bf(B[(size_t)(rowoff[s] + k) * 256 + n]);
}

// ---------------------------------------------------------------------------
// General LDS-free bf16 MFMA GEMM (64x64 tile, grid (ceil(M/64),4)) for FFNs.
// ---------------------------------------------------------------------------
__global__ __launch_bounds__(256) void gemm_kernel(
    const void* __restrict__ Av, int a_is_f32, int M, int K,
    const unsigned short* __restrict__ Bp,
    const float* __restrict__ bias, const float* __restrict__ resid,
    unsigned short* __restrict__ Cb, float* __restrict__ Cf, int do_gelu) {
    int lane = threadIdx.x & 63;
    int w = threadIdx.x >> 6;
    int row0 = blockIdx.x * 64 + w * 16;
    int n0 = blockIdx.y * 64;
    int m15 = lane & 15, quad = lane >> 4;

    int arow = row0 + m15;
    if (arow > M - 1) arow = M - 1;

    f32x4 acc[4] = {{0,0,0,0},{0,0,0,0},{0,0,0,0},{0,0,0,0}};
    const float* Af = (const float*)Av + (size_t)arow * K + quad * 8;
    const unsigned short* Ab = (const unsigned short*)Av + (size_t)arow * K + quad * 8;

    for (int kt = 0; kt < K; kt += 32) {
        short8 a;
        if (a_is_f32) {
            f32x4 lo = *(const f32x4*)(Af + kt);
            f32x4 hi = *(const f32x4*)(Af + kt + 4);
#pragma unroll
            for (int j = 0; j < 4; ++j) {
                a[j] = (short)f2bf(lo[j]);
                a[j + 4] = (short)f2bf(hi[j]);
            }
        } else {
            a = *(const short8*)(Ab + kt);
        }
        const unsigned short* bbase =
            Bp + ((((size_t)(kt >> 5) * 16 + (n0 >> 4)) * 64 + lane) << 3);
#pragma unroll
        for (int nt = 0; nt < 4; ++nt) {
            short8 b = *(const short8*)(bbase + nt * 64 * 8);
            acc[nt] = __builtin_amdgcn_mfma_f32_16x16x32_bf16(a, b, acc[nt], 0, 0, 0);
        }
    }

#pragma unroll
    for (int nt = 0; nt < 4; ++nt) {
        int col = n0 + nt * 16 + m15;
        float bv = bias ? bias[col] : 0.f;
#pragma unroll
        for (int r = 0; r < 4; ++r) {
            int row = row0 + quad * 4 + r;
            if (row < M) {
                float v = acc[nt][r] + bv;
                if (do_gelu) v = gelu_f(v);
                size_t idx = (size_t)row * 256 + col;
                if (resid) v += resid[idx];
                if (Cb) Cb[idx] = f2bf(v);
                if (Cf) Cf[idx] = v;
            }
        }
    }
}

// ---------------------------------------------------------------------------
// P and Q in one dispatch: grid ((M+63)/64, 8); y<4 -> P cols, y>=4 -> Q cols.
// ---------------------------------------------------------------------------
__global__ __launch_bounds__(256) void pq_kernel(
    const unsigned short* __restrict__ A, int M,
    const unsigned short* __restrict__ BpA, const unsigned short* __restrict__ BpB,
    const float* __restrict__ qbias,
    unsigned short* __restrict__ Pb, unsigned short* __restrict__ Qb) {
    int lane = threadIdx.x & 63;
    int w = threadIdx.x >> 6;
    int row0 = blockIdx.x * 64 + w * 16;
    int isQ = blockIdx.y >> 2;
    int n0 = (blockIdx.y & 3) * 64;
    const unsigned short* Bp = isQ ? BpB : BpA;
    unsigned short* out = isQ ? Qb : Pb;
    int m15 = lane & 15, quad = lane >> 4;

    int arow = row0 + m15;
    if (arow > M - 1) arow = M - 1;
    const unsigned short* Ab = A + (size_t)arow * 256 + quad * 8;

    f32x4 acc[4] = {{0,0,0,0},{0,0,0,0},{0,0,0,0},{0,0,0,0}};
    for (int kt = 0; kt < 256; kt += 32) {
        short8 a = *(const short8*)(Ab + kt);
        const unsigned short* bbase =
            Bp + ((((size_t)(kt >> 5) * 16 + (n0 >> 4)) * 64 + lane) << 3);
#pragma unroll
        for (int nt = 0; nt < 4; ++nt) {
            short8 b = *(const short8*)(bbase + nt * 64 * 8);
            acc[nt] = __builtin_amdgcn_mfma_f32_16x16x32_bf16(a, b, acc[nt], 0, 0, 0);
        }
    }

#pragma unroll
    for (int nt = 0; nt < 4; ++nt) {
        int col = n0 + nt * 16 + m15;
        float bv = isQ ? qbias[col] : 0.f;
#pragma unroll
        for (int r = 0; r < 4; ++r) {
            int row = row0 + quad * 4 + r;
            if (row < M) out[(size_t)row * 256 + col] = f2bf(acc[nt][r] + bv);
        }
    }
}

// ---------------------------------------------------------------------------
// Counting sort by dst: zero -> histogram -> single-block scan -> scatter.
// ---------------------------------------------------------------------------
__global__ void zero_i32(int* __restrict__ p, int n) {
    int i = blockIdx.x * 256 + threadIdx.x;
    if (i < n) p[i] = 0;
}
__global__ void hist_kernel(const int* __restrict__ dst, int* __restrict__ cnt, int E) {
    int e = blockIdx.x * 256 + threadIdx.x;
    if (e < E) atomicAdd(&cnt[dst[e]], 1);
}
__global__ __launch_bounds__(1024) void scan_kernel(const int* __restrict__ cnt,
                                                    int* __restrict__ cursor, int N) {
    __shared__ int part[1024];
    int tid = threadIdx.x;
    int per = (N + 1023) / 1024;
    int lo = tid * per;
    int s = 0;
    for (int j = 0; j < per; ++j) {
        int idx = lo + j;
        if (idx < N) s += cnt[idx];
    }
    part[tid] = s;
    __syncthreads();
    for (int off = 1; off < 1024; off <<= 1) {
        int t = (tid >= off) ? part[tid - off] : 0;
        __syncthreads();
        part[tid] += t;
        __syncthreads();
    }
    int run = (tid > 0) ? part[tid - 1] : 0;
    for (int j = 0; j < per; ++j) {
        int idx = lo + j;
        if (idx < N) {
            cursor[idx] = run;
            run += cnt[idx];
        }
    }
}
__global__ void scatter_kernel(const int* __restrict__ src, const int* __restrict__ dst,
                               int* __restrict__ cursor, int* __restrict__ perm,
                               int* __restrict__ srcs, int* __restrict__ dsts, int E) {
    int e = blockIdx.x * 256 + threadIdx.x;
    if (e < E) {
        int d = dst[e];
        int pos = atomicAdd(&cursor[d], 1);
        perm[pos] = e;
        srcs[pos] = src[e];
        dsts[pos] = d;
    }
}

// ---------------------------------------------------------------------------
// FUSED edge kernel. Block = 256 threads (4 waves) = one 64-edge tile.
// Phase 1: R[64x256] -> swizzled LDS (wave w: rows w*16..+15, acc[16]).
// Phase 2: wave w walks its own 16 rows, 4 ch/lane uint2, 16-deep prefetch.
//   Interior-to-window segments: plain RMW. First/last partials -> carry.
// Merge: 256-thread segmented merge of the 8-entry carry chain; interior
//   runs plain RMW, boundary runs atomicAdd.
// ---------------------------------------------------------------------------
__global__ __launch_bounds__(256, 4) void fused_kernel(
    const float* __restrict__ ef, const int* __restrict__ perm,
    const int* __restrict__ srcs, const int* __restrict__ dsts,
    const unsigned short* __restrict__ BpC,
    const unsigned short* __restrict__ Pb, const unsigned short* __restrict__ Qb,
    const int* __restrict__ cursor, const int* __restrict__ cnt,
    float* __restrict__ Hacc, int E) {
    __shared__ unsigned short tiles[64 * 256];  // 32 KB R tile (swizzled)
    // carry region aliased onto tiles after phase 2 (R dead by then):
    float* Fr = (float*)tiles;            // [4][256]
    float* Lr = Fr + 4 * 256;             // [4][256]
    int* Cd = (int*)(Lr + 4 * 256);       // [8]: Fd[0..3], Ld[0..3]

    int lane = threadIdx.x & 63;
    int w = threadIdx.x >> 6;  // 0..3
    int e_lo = blockIdx.x * 64;
    int n_e = E - e_lo;
    if (n_e > 64) n_e = 64;
    int e_hi = e_lo + n_e;
    int base = w * 16;
    int m15 = lane & 15, quad = lane >> 4;
    int c0 = lane << 2;  // channel base, 4 ch/lane

    // per-wave edge regs: lane&15 holds edge base+(lane&15) of this tile
    int myi = base + (lane & 15);
    int mye = e_lo + myi;
    if (mye > E - 1) mye = E - 1;
    int vsw = srcs[mye];
    int vdw = dsts[mye];

    // hoist initial segment state (latency hides under phase-1 MFMA)
    int cur_d = -2;
    uint2 qu = {0u, 0u};
    if (base < n_e) {
        cur_d = __builtin_amdgcn_readlane(vdw, 0);
        qu = *(const uint2*)(Qb + (((size_t)cur_d) << 8) + c0);
    }
    int fd_first = cur_d;

    // ---- Phase 1: rgemm body, wave w -> rows base..base+15 ----
    {
        int ar = e_lo + base + m15;
        if (ar > E - 1) ar = E - 1;
        int g = perm[ar];
        const float* A = ef + (size_t)g * 64 + quad * 8;

        f32x4 acc[16];
#pragma unroll
        for (int i = 0; i < 16; ++i) acc[i] = {0.f, 0.f, 0.f, 0.f};

#pragma unroll
        for (int kb = 0; kb < 2; ++kb) {
            f32x4 lo = *(const f32x4*)(A + kb * 32);
            f32x4 hi = *(const f32x4*)(A + kb * 32 + 4);
            short8 a;
#pragma unroll
            for (int j = 0; j < 4; ++j) {
                a[j] = (short)f2bf(lo[j]);
                a[j + 4] = (short)f2bf(hi[j]);
            }
            const unsigned short* bb = BpC + (((size_t)kb * 16 * 64 + lane) << 3);
#pragma unroll
            for (int nt = 0; nt < 16; ++nt) {
                short8 b = *(const short8*)(bb + (size_t)nt * 64 * 8);
                acc[nt] = __builtin_amdgcn_mfma_f32_16x16x32_bf16(a, b, acc[nt], 0, 0, 0);
            }
        }

        // swizzled store: col' = ((nt^quad)<<4)+m15; row = base+quad*4+r
        // (row>>2)&3 == quad for r<4, so read-side swizzle uses (k>>2)&3.
#pragma unroll
        for (int nt = 0; nt < 16; ++nt) {
            int colp = ((nt ^ quad) << 4) + m15;
#pragma unroll
            for (int r = 0; r < 4; ++r) {
                int row = base + quad * 4 + r;
                tiles[row * 256 + colp] = f2bf(acc[nt][r]);
            }
        }
    }
    // NO barrier: wave w's phase 2 reads only rows it wrote itself.

    // ---- Phase 2: walk own 16 rows, 4 ch/lane ----
    float s0 = 0.f, s1 = 0.f, s2 = 0.f, s3 = 0.f;
    float F0 = 0.f, F1 = 0.f, F2 = 0.f, F3 = 0.f;
    int lastd = -2;
    int emitted = 0;

    if (n_e == 64) {
        // load all 16 P rows (uint2 gather, scalar-addressed) + 16 R rows
        uint2 pu[16], ru[16];
#pragma unroll
        for (int j = 0; j < 16; ++j) {
            int s = __builtin_amdgcn_readlane(vsw, j);
            pu[j] = *(const uint2*)(Pb + (((size_t)s) << 8) + c0);
            int k = base + j;
            // read-side unswizzle: group (lane>>2) ^ ((j>>2)&3)  (w*4%4==0)
            int off = (((lane >> 2) ^ ((j >> 2) & 3)) << 4) + ((lane & 3) << 2);
            ru[j] = *(const uint2*)(tiles + k * 256 + off);
        }
#pragma unroll
        for (int j = 0; j < 16; ++j) {
            if (j > 0) {
                int d = __builtin_amdgcn_readlane(vdw, j);
                if (d != cur_d) {
                    if (!emitted) {
                        F0 = s0; F1 = s1; F2 = s2; F3 = s3;
                        emitted = 1;
                    } else {
                        // segment interior to this window: unique writer
                        float* hp = Hacc + (((size_t)cur_d) << 8) + c0;
                        hp[0] += s0; hp[1] += s1; hp[2] += s2; hp[3] += s3;
                    }
                    s0 = s1 = s2 = s3 = 0.f;
                    cur_d = d;
                    qu = *(const uint2*)(Qb + (((size_t)d) << 8) + c0);
                }
            }
            float q0 = lo16(qu.x), q1 = hi16(qu.x);
            float q2 = lo16(qu.y), q3 = hi16(qu.y);
            s0 += gelu_f(lo16(pu[j].x) + q0 + lo16(ru[j].x));
            s1 += gelu_f(hi16(pu[j].x) + q1 + hi16(ru[j].x));
            s2 += gelu_f(lo16(pu[j].y) + q2 + lo16(ru[j].y));
            s3 += gelu_f(hi16(pu[j].y) + q3 + hi16(ru[j].y));
        }
        if (!emitted) {
            F0 = s0; F1 = s1; F2 = s2; F3 = s3;  // single-run window
            lastd = -2;
        } else {
            lastd = cur_d;
        }
    } else {
        // tail tile (unused when E%64==0): guarded walk, same carry logic
        int lim = n_e - base;
        if (lim < 0) lim = 0;
        if (lim > 16) lim = 16;
        if (lim == 0) { fd_first = -2; lastd = -2; }
        for (int j = 0; j < lim; ++j) {
            if (j > 0) {
                int d = __builtin_amdgcn_readlane(vdw, j);
                if (d != cur_d) {
                    if (!emitted) {
                        F0 = s0; F1 = s1; F2 = s2; F3 = s3;
                        emitted = 1;
                    } else {
                        float* hp = Hacc + (((size_t)cur_d) << 8) + c0;
                        hp[0] += s0; hp[1] += s1; hp[2] += s2; hp[3] += s3;
                    }
                    s0 = s1 = s2 = s3 = 0.f;
                    cur_d = d;
                    qu = *(const uint2*)(Qb + (((size_t)d) << 8) + c0);
                }
            }
            int s = __builtin_amdgcn_readlane(vsw, j);
            uint2 pv = *(const uint2*)(Pb + (((size_t)s) << 8) + c0);
            int k = base + j;
            int off = (((lane >> 2) ^ ((k >> 2) & 3)) << 4) + ((lane & 3) << 2);
            uint2 rv = *(const uint2*)(tiles + k * 256 + off);
            s0 += gelu_f(lo16(pv.x) + lo16(qu.x) + lo16(rv.x));
            s1 += gelu_f(hi16(pv.x) + hi16(qu.x) + hi16(rv.x));
            s2 += gelu_f(lo16(pv.y) + lo16(qu.y) + lo16(rv.y));
            s3 += gelu_f(hi16(pv.y) + hi16(qu.y) + hi16(rv.y));
        }
        if (lim > 0) {
            if (!emitted) {
                F0 = s0; F1 = s1; F2 = s2; F3 = s3;
                lastd = -2;
            } else {
                lastd = cur_d;
            }
        }
    }

    __syncthreads();  // all waves done reading R tile -> alias as carries

    // write carries (Fr/Lr alias the dead R tile)
    Fr[w * 256 + c0 + 0] = F0;
    Fr[w * 256 + c0 + 1] = F1;
    Fr[w * 256 + c0 + 2] = F2;
    Fr[w * 256 + c0 + 3] = F3;
    Lr[w * 256 + c0 + 0] = s0;
    Lr[w * 256 + c0 + 1] = s1;
    Lr[w * 256 + c0 + 2] = s2;
    Lr[w * 256 + c0 + 3] = s3;
    if (lane == 0) {
        Cd[w] = fd_first;
        Cd[4 + w] = lastd;
    }
    __syncthreads();

    // ---- segmented merge of the 8-entry chain (F0 L0 F1 L1 F2 L2 F3 L3) ----
    {
        int ch = threadIdx.x;  // one channel per thread
        float rv = 0.f;
        int rd = -1;
#pragma unroll
        for (int i = 0; i < 8; ++i) {
            int wi = i >> 1;
            int d = (i & 1) ? Cd[4 + wi] : Cd[wi];
            if (d < 0) continue;
            float v = (i & 1) ? Lr[wi * 256 + ch] : Fr[wi * 256 + ch];
            if (d == rd) {
                rv += v;
            } else {
                if (rd >= 0) {
                    int end = cursor[rd], beg = end - cnt[rd];
                    size_t hidx = (((size_t)rd) << 8) + ch;
                    if (beg >= e_lo && end <= e_hi)
                        Hacc[hidx] += rv;
                    else
                        atomicAdd(&Hacc[hidx], rv);
                }
                rd = d;
                rv = v;
            }
        }
        if (rd >= 0) {
            int end = cursor[rd], beg = end - cnt[rd];
            size_t hidx = (((size_t)rd) << 8) + ch;
            if (beg >= e_lo && end <= e_hi)
                Hacc[hidx] += rv;
            else
                atomicAdd(&Hacc[hidx], rv);
        }
    }
}

// ---------------------------------------------------------------------------
// h_bf = bf16(Hacc), vectorized (float4 -> uint2). n4 = N*256/4.
// ---------------------------------------------------------------------------
__global__ void finalize_h(const float* __restrict__ Hacc,
                           unsigned short* __restrict__ h_bf, int n4) {
    int i = blockIdx.x * 256 + threadIdx.x;
    if (i < n4) {
        float4 v = ((const float4*)Hacc)[i];
        uint2 o;
        o.x = (unsigned int)f2bf(v.x) | ((unsigned int)f2bf(v.y) << 16);
        o.y = (unsigned int)f2bf(v.z) | ((unsigned int)f2bf(v.w) << 16);
        ((uint2*)h_bf)[i] = o;
    }
}

// ---------------------------------------------------------------------------
extern "C" void kernel_launch(void* const* d_in, const int* in_sizes, int n_in,
                              void* d_out, int out_size, void* d_ws, size_t ws_size,
                              hipStream_t stream) {
    const float* x     = (const float*)d_in[0];
    const int*   ei    = (const int*)d_in[1];
    const float* ef    = (const float*)d_in[2];
    const float* W_ff1 = (const float*)d_in[3];
    const float* b_ff1 = (const float*)d_in[4];
    const float* W_mp1 = (const float*)d_in[5];
    const float* b_mp1 = (const float*)d_in[6];
    const float* W_mp2 = (const float*)d_in[7];
    const float* b_mp2 = (const float*)d_in[8];
    const float* W_ff2 = (const float*)d_in[9];
    const float* b_ff2 = (const float*)d_in[10];

    const int N = in_sizes[0] / 256;  // 10000
    const int E = in_sizes[1] / 2;    // 320000
    const int* src = ei;
    const int* dst = ei + E;

    // ---- workspace carve (256B-aligned bumps) ----
    char* p = (char*)d_ws;
    unsigned short* h_bf = (unsigned short*)p;  p += ((size_t)N * 256 * 2 + 255) & ~255ull;
    unsigned short* Pbuf = (unsigned short*)p;  p += ((size_t)N * 256 * 2 + 255) & ~255ull;
    unsigned short* Qbuf = (unsigned short*)p;  p += ((size_t)N * 256 * 2 + 255) & ~255ull;
    float* Hacc = (float*)p;                    p += ((size_t)N * 256 * 4 + 255) & ~255ull;
    unsigned short* Bp = (unsigned short*)p;    p += (425984ull * 2 + 255) & ~255ull;
    int* cnt    = (int*)p;                      p += ((size_t)N * 4 + 255) & ~255ull;
    int* cursor = (int*)p;                      p += ((size_t)N * 4 + 255) & ~255ull;
    int* perm   = (int*)p;                      p += ((size_t)E * 4 + 255) & ~255ull;
    int* srcs   = (int*)p;                      p += ((size_t)E * 4 + 255) & ~255ull;
    int* dsts   = (int*)p;                      p += ((size_t)E * 4 + 255) & ~255ull;

    unsigned short* Bp_ff1 = Bp + 0;
    unsigned short* Bp_a1  = Bp + 65536;
    unsigned short* Bp_b1  = Bp + 131072;
    unsigned short* Bp_c1  = Bp + 196608;
    unsigned short* Bp_a2  = Bp + 212992;
    unsigned short* Bp_b2  = Bp + 278528;
    unsigned short* Bp_c2  = Bp + 344064;
    unsigned short* Bp_ff2 = Bp + 360448;

    // ---- repack all weights (single dispatch) ----
    repack_all<<<1664, 256, 0, stream>>>(W_ff1, W_mp1, W_mp2, W_ff2, Bp);

    // ---- counting sort of edges by dst (CSR) ----
    zero_i32<<<(N + 255) / 256, 256, 0, stream>>>(cnt, N);
    hist_kernel<<<(E + 255) / 256, 256, 0, stream>>>(dst, cnt, E);
    scan_kernel<<<1, 1024, 0, stream>>>(cnt, cursor, N);
    scatter_kernel<<<(E + 255) / 256, 256, 0, stream>>>(src, dst, cursor, perm, srcs,
                                                        dsts, E);

    dim3 gN((N + 63) / 64, 4);
    dim3 gPQ((N + 63) / 64, 8);
    int n_tiles = (E + 63) / 64;

    // ---- FFN1: h = gelu(x@W_ff1 + b); h_bf for GEMMs, Hacc = f32 accumulator
    gemm_kernel<<<gN, 256, 0, stream>>>(x, 1, N, 256, Bp_ff1, b_ff1, nullptr,
                                        h_bf, Hacc, 1);

    const unsigned short* Bp_a[2] = {Bp_a1, Bp_a2};
    const unsigned short* Bp_b[2] = {Bp_b1, Bp_b2};
    const unsigned short* Bp_c[2] = {Bp_c1, Bp_c2};
    const float* bmp[2] = {b_mp1, b_mp2};

    for (int l = 0; l < 2; ++l) {
        pq_kernel<<<gPQ, 256, 0, stream>>>(h_bf, N, Bp_a[l], Bp_b[l], bmp[l],
                                           Pbuf, Qbuf);
        fused_kernel<<<n_tiles, 256, 0, stream>>>(
            ef, perm, srcs, dsts, Bp_c[l], Pbuf, Qbuf, cursor, cnt, Hacc, E);
        if (l == 0)
            finalize_h<<<(N * 64 + 255) / 256, 256, 0, stream>>>(Hacc, h_bf, N * 64);
    }

    // ---- FFN2: out = x + bf16(Hacc)@W_ff2 + b  (reads Hacc directly) ----
    gemm_kernel<<<gN, 256, 0, stream>>>(Hacc, 1, N, 256, Bp_ff2, b_ff2, x,
                                        nullptr, (float*)d_out, 0);
}